// Round 3
// baseline (60.382 us; speedup 1.0000x reference)
//
#include <hip/hip_runtime.h>

// B=8, C=512, T=8192, RATIO=2, K=12
#define T_LEN 8192
#define C_N   512
#define BLOCK 256
#define OPT   16                      // outputs per thread
#define TCHUNK (BLOCK * OPT)          // 4096
#define NCHUNK (T_LEN / TCHUNK)       // 2
#define INV_2PI 0.15915494309189535f

// Verified formulas (ground truth = round-0/1 passing kernels):
//   y[2i]   = 2 * sum_t wup[2t+1] * xc[i+2-t]   (t=0..5, xc = edge-clamped x)
//   y[2i+1] = 2 * sum_t wup[2t]   * xc[i+3-t]
//   snake:   y += sin(a*y)^2 / (a+1e-9)
//   out[n]  = sum_k wdn[k] * ypad[2n-5+k]       (ypad = edge-clamped y)
//
// Mapping: lane handles outputs N..N+15, N = chunk*4096 + 16*tid.
//   own pairs i = N-3..N+12 -> yv[u] = y[2N-6+u], u=0..31
//   halo h[v] = y[2N+26+v], v=0..10  <- lane+1's yv[0..10] via shfl_down
//   lane 63 computes halo itself (pairs i = N+13..N+18, x up to xc[N+20])
//   Y[j] = y[2N-5+j] = (j<31 ? yv[j+1] : h[j-31]),  out[N+r]=sum_k wdn[k]*Y[2r+k]

__global__ __launch_bounds__(BLOCK) void act1d_fused(
    const float* __restrict__ x,
    const float* __restrict__ alpha,
    const float* __restrict__ wup_g,
    const float* __restrict__ wdn_g,
    float* __restrict__ out)
{
    const int bx    = blockIdx.x;
    const int chunk = bx & (NCHUNK - 1);
    const int bc    = bx >> 1;
    const int c     = bc & (C_N - 1);
    const int tid   = threadIdx.x;
    const int lane  = tid & 63;
    const int N     = chunk * TCHUNK + OPT * tid;   // first output of this lane

    const float* __restrict__ xrow = x   + (size_t)bc * T_LEN;
    float*       __restrict__ orow = out + (size_t)bc * T_LEN;

    // ---- uniform constants ----
    float u2[12], wdn[12];
#pragma unroll
    for (int i = 0; i < 12; ++i) {
        u2[i]  = wup_g[i] + wup_g[i];   // fold the *2 of the transposed conv
        wdn[i] = wdn_g[i];
    }
    const float a     = __expf(alpha[c]);
    const float inv_a = 1.0f / (a + 1e-9f);
    const float ka    = a * INV_2PI;    // v_sin_f32 takes revolutions

    // ---- x window: xr[u] = xc[N-8+u], u=0..23 (6 independent dwordx4) ----
    float xr[24];
    if (N >= 8) {
#pragma unroll
        for (int w = 0; w < 6; ++w) {
            const float4 t4 = *reinterpret_cast<const float4*>(xrow + N - 8 + 4 * w);
            xr[4 * w + 0] = t4.x;
            xr[4 * w + 1] = t4.y;
            xr[4 * w + 2] = t4.z;
            xr[4 * w + 3] = t4.w;
        }
    } else {   // only N==0: left edge clamp
#pragma unroll
        for (int u = 0; u < 24; ++u)
            xr[u] = xrow[max(N - 8 + u, 0)];
    }

    // ---- own 16 pairs: upsample, in registers ----
    float yv[32];
#pragma unroll
    for (int p = 0; p < 16; ++p) {
        float ae = 0.0f, ao = 0.0f;
#pragma unroll
        for (int t = 0; t < 6; ++t) {
            ae = fmaf(u2[2 * t + 1], xr[7 + p - t], ae);   // y[2(N-3+p)]
            ao = fmaf(u2[2 * t],     xr[8 + p - t], ao);   // y[2(N-3+p)+1]
        }
        yv[2 * p]     = ae;
        yv[2 * p + 1] = ao;
    }
    // ---- snake ----
#pragma unroll
    for (int q = 0; q < 32; ++q) {
        const float s = __builtin_amdgcn_sinf(ka * yv[q]);  // sin(a*y)
        yv[q] = fmaf(s * s, inv_a, yv[q]);
    }

    // ---- left edge: ypad[m<0] = y[0] (= yv[6] when N==0) ----
    if (N == 0) {
        yv[1] = yv[2] = yv[3] = yv[4] = yv[5] = yv[6];
    }

    // ---- halo from lane+1 ----
    float h[11];
#pragma unroll
    for (int v = 0; v < 11; ++v)
        h[v] = __shfl_down(yv[v], 1, 64);

    // ---- lane 63: compute halo itself (pairs i = N+13..N+18) ----
    if (lane == 63) {
        float xh[5];   // xh[u] = xc[N+16+u], u=0..4
#pragma unroll
        for (int u = 0; u < 5; ++u)
            xh[u] = xrow[min(N + 16 + u, T_LEN - 1)];
        // XX(u) = xc[N-8+u]: u<24 -> xr[u], else xh[u-24]  (u compile-time)
#define XX(u) ((u) < 24 ? xr[(u) < 24 ? (u) : 0] : xh[(u) >= 24 ? (u) - 24 : 0])
#pragma unroll
        for (int pp = 0; pp < 6; ++pp) {
            // even: h[2pp] = y[2(N+13+pp)], taps XX(23+pp-t)
            float ae = 0.0f;
#pragma unroll
            for (int t = 0; t < 6; ++t)
                ae = fmaf(u2[2 * t + 1], XX(23 + pp - t), ae);
            {
                const float s = __builtin_amdgcn_sinf(ka * ae);
                ae = fmaf(s * s, inv_a, ae);
            }
            h[2 * pp] = ae;
            if (pp < 5) {
                // odd: h[2pp+1] = y[2(N+13+pp)+1], taps XX(24+pp-t)
                float ao = 0.0f;
#pragma unroll
                for (int t = 0; t < 6; ++t)
                    ao = fmaf(u2[2 * t], XX(24 + pp - t), ao);
                const float s = __builtin_amdgcn_sinf(ka * ao);
                ao = fmaf(s * s, inv_a, ao);
                h[2 * pp + 1] = ao;
            }
        }
#undef XX
    }

    // ---- right edge: ypad[m>16383] = y[16383] (= h[5] when N==T-16) ----
    if (N == T_LEN - OPT) {
        h[6] = h[7] = h[8] = h[9] = h[10] = h[5];
    }

    // ---- downsample: out[N+r] = sum_k wdn[k] * Y[2r+k] ----
    float o[OPT];
#pragma unroll
    for (int r = 0; r < OPT; ++r) {
        float acc = 0.0f;
#pragma unroll
        for (int k = 0; k < 12; ++k) {
            const int j = 2 * r + k;
            acc = fmaf(wdn[k], (j < 31 ? yv[j + 1] : h[j - 31]), acc);
        }
        o[r] = acc;
    }

#pragma unroll
    for (int w = 0; w < 4; ++w)
        *reinterpret_cast<float4*>(orow + N + 4 * w) =
            make_float4(o[4 * w], o[4 * w + 1], o[4 * w + 2], o[4 * w + 3]);
}

extern "C" void kernel_launch(void* const* d_in, const int* in_sizes, int n_in,
                              void* d_out, int out_size, void* d_ws, size_t ws_size,
                              hipStream_t stream)
{
    const float* x     = (const float*)d_in[0];
    const float* alpha = (const float*)d_in[1];
    const float* wup   = (const float*)d_in[2];
    const float* wdn   = (const float*)d_in[3];
    float*       out   = (float*)d_out;

    const int B_N  = out_size / (C_N * T_LEN);   // 8
    const int grid = B_N * C_N * NCHUNK;         // 8192

    act1d_fused<<<grid, BLOCK, 0, stream>>>(x, alpha, wup, wdn, out);
}

// Round 4
// 55.881 us; speedup vs baseline: 1.0805x; 1.0805x over previous
//
#include <hip/hip_runtime.h>

// B=8, C=512, T=8192, RATIO=2, K=12
#define T_LEN 8192
#define C_N   512
#define BLOCK 256
#define OPT   8                       // outputs per thread per segment
#define TCHUNK (BLOCK * OPT)          // 2048
#define INV_2PI 0.15915494309189535f

typedef float f32x4 __attribute__((ext_vector_type(4)));

// Verified formulas (ground truth = round-0/1 passing kernels):
//   y[2i]   = 2 * sum_t wup[2t+1] * xc[i+2-t]   (t=0..5, xc = edge-clamped x)
//   y[2i+1] = 2 * sum_t wup[2t]   * xc[i+3-t]
//   snake:   y += sin(a*y)^2 / (a+1e-9)
//   out[n]  = sum_k wdn[k] * ypad[2n-5+k]       (ypad = edge-clamped y)
//
// Mapping (per segment, = R1 winner): lane outputs N..N+7.
//   own pairs i = N-3..N+4  -> yv[u] = y[2N-6+u], u=0..15
//   halo h[v] = y[2N+10+v], v=0..10  <- lane+1's yv[0..10] via shfl_down
//   lane 63 computes halo itself; Y[j] = (j<15 ? yv[j+1] : h[j-15])
//
// R3: two segments per thread (chunks p and p+2, 4096 apart) for memory-level
// parallelism; nontemporal output stores to preserve x's L3 residency.

__device__ __forceinline__ void load_xr(const float* __restrict__ xrow,
                                        int N, float xr[16])
{
    if (N >= 8) {
#pragma unroll
        for (int w = 0; w < 4; ++w) {
            const float4 t4 = *reinterpret_cast<const float4*>(xrow + N - 8 + 4 * w);
            xr[4 * w + 0] = t4.x;
            xr[4 * w + 1] = t4.y;
            xr[4 * w + 2] = t4.z;
            xr[4 * w + 3] = t4.w;
        }
    } else {   // only N==0: left edge clamp
#pragma unroll
        for (int u = 0; u < 16; ++u)
            xr[u] = xrow[max(N - 8 + u, 0)];
    }
}

__device__ __forceinline__ void compute_segment(
    const float xr[16], int N, int lane,
    const float* __restrict__ xrow, float* __restrict__ orow,
    const float u2[12], const float wdn[12],
    float inv_a, float ka)
{
    // ---- own 8 pairs: upsample ----
    float yv[16];
#pragma unroll
    for (int p = 0; p < 8; ++p) {
        float ae = 0.0f, ao = 0.0f;
#pragma unroll
        for (int t = 0; t < 6; ++t) {
            ae = fmaf(u2[2 * t + 1], xr[7 + p - t], ae);   // y[2(N-3+p)]
            ao = fmaf(u2[2 * t],     xr[8 + p - t], ao);   // y[2(N-3+p)+1]
        }
        yv[2 * p]     = ae;
        yv[2 * p + 1] = ao;
    }
    // ---- snake ----
#pragma unroll
    for (int q = 0; q < 16; ++q) {
        const float s = __builtin_amdgcn_sinf(ka * yv[q]);  // sin(a*y)
        yv[q] = fmaf(s * s, inv_a, yv[q]);
    }

    // ---- left edge: ypad[m<0] = y[0] (= yv[6] when N==0) ----
    if (N == 0) {
        yv[1] = yv[2] = yv[3] = yv[4] = yv[5] = yv[6];
    }

    // ---- halo from lane+1 ----
    float h[11];
#pragma unroll
    for (int v = 0; v < 11; ++v)
        h[v] = __shfl_down(yv[v], 1, 64);

    // ---- lane 63: compute halo itself (pairs i = N+5..N+10) ----
    if (lane == 63) {
        float xh[6];   // xh[u] = xc[N+8+u], u=0..5
        if (N + 13 < T_LEN) {
            const float4 A = *reinterpret_cast<const float4*>(xrow + N + 8);
            const float4 Bv = *reinterpret_cast<const float4*>(xrow + N + 12);
            xh[0]=A.x; xh[1]=A.y; xh[2]=A.z; xh[3]=A.w; xh[4]=Bv.x; xh[5]=Bv.y;
        } else {
#pragma unroll
            for (int u = 0; u < 6; ++u)
                xh[u] = xrow[min(N + 8 + u, T_LEN - 1)];
        }
        // XX(u) = xc[N-8+u]: u<16 -> xr[u], else xh[u-16]  (u compile-time)
#define XX(u) ((u) < 16 ? xr[(u) < 16 ? (u) : 0] : xh[(u) >= 16 ? (u) - 16 : 0])
#pragma unroll
        for (int pp = 0; pp < 6; ++pp) {
            float ae = 0.0f;   // h[2pp] = y[2(N+5+pp)], taps XX(15+pp-t)
#pragma unroll
            for (int t = 0; t < 6; ++t)
                ae = fmaf(u2[2 * t + 1], XX(15 + pp - t), ae);
            {
                const float s = __builtin_amdgcn_sinf(ka * ae);
                ae = fmaf(s * s, inv_a, ae);
            }
            h[2 * pp] = ae;
            if (pp < 5) {
                float ao = 0.0f;   // h[2pp+1] = y[2(N+5+pp)+1], taps XX(16+pp-t)
#pragma unroll
                for (int t = 0; t < 6; ++t)
                    ao = fmaf(u2[2 * t], XX(16 + pp - t), ao);
                const float s = __builtin_amdgcn_sinf(ka * ao);
                ao = fmaf(s * s, inv_a, ao);
                h[2 * pp + 1] = ao;
            }
        }
#undef XX
    }

    // ---- right edge: ypad[m>16383] = y[16383] (= h[5] when N==T-8) ----
    if (N == T_LEN - OPT) {
        h[6] = h[7] = h[8] = h[9] = h[10] = h[5];
    }

    // ---- downsample ----
    float o[OPT];
#pragma unroll
    for (int r = 0; r < OPT; ++r) {
        float acc = 0.0f;
#pragma unroll
        for (int k = 0; k < 12; ++k) {
            const int j = 2 * r + k;
            acc = fmaf(wdn[k], (j < 15 ? yv[j + 1] : h[j - 15]), acc);
        }
        o[r] = acc;
    }

    // ---- nontemporal stores (out is never re-read; keep x L3-resident) ----
    f32x4 s0 = { o[0], o[1], o[2], o[3] };
    f32x4 s1 = { o[4], o[5], o[6], o[7] };
    __builtin_nontemporal_store(s0, reinterpret_cast<f32x4*>(orow + N));
    __builtin_nontemporal_store(s1, reinterpret_cast<f32x4*>(orow + N + 4));
}

__global__ __launch_bounds__(BLOCK) void act1d_fused(
    const float* __restrict__ x,
    const float* __restrict__ alpha,
    const float* __restrict__ wup_g,
    const float* __restrict__ wdn_g,
    float* __restrict__ out)
{
    const int bx   = blockIdx.x;
    const int p    = bx & 1;            // chunk-pair selector
    const int bc   = bx >> 1;           // row index b*C + c
    const int c    = bc & (C_N - 1);
    const int tid  = threadIdx.x;
    const int lane = tid & 63;

    const int NA = p * TCHUNK + OPT * tid;          // chunk p      (0 or 1)
    const int NB = (p + 2) * TCHUNK + OPT * tid;    // chunk p+2    (2 or 3)

    const float* __restrict__ xrow = x   + (size_t)bc * T_LEN;
    float*       __restrict__ orow = out + (size_t)bc * T_LEN;

    // ---- issue all 8 global loads up front (2 segments x 4 dwordx4) ----
    float xrA[16], xrB[16];
    load_xr(xrow, NA, xrA);
    load_xr(xrow, NB, xrB);

    // ---- uniform constants (scalar path) ----
    float u2[12], wdn[12];
#pragma unroll
    for (int i = 0; i < 12; ++i) {
        u2[i]  = wup_g[i] + wup_g[i];   // fold the *2 of the transposed conv
        wdn[i] = wdn_g[i];
    }
    const float a     = __expf(alpha[c]);
    const float inv_a = 1.0f / (a + 1e-9f);
    const float ka    = a * INV_2PI;    // v_sin_f32 takes revolutions

    compute_segment(xrA, NA, lane, xrow, orow, u2, wdn, inv_a, ka);
    compute_segment(xrB, NB, lane, xrow, orow, u2, wdn, inv_a, ka);
}

extern "C" void kernel_launch(void* const* d_in, const int* in_sizes, int n_in,
                              void* d_out, int out_size, void* d_ws, size_t ws_size,
                              hipStream_t stream)
{
    const float* x     = (const float*)d_in[0];
    const float* alpha = (const float*)d_in[1];
    const float* wup   = (const float*)d_in[2];
    const float* wdn   = (const float*)d_in[3];
    float*       out   = (float*)d_out;

    const int B_N  = out_size / (C_N * T_LEN);   // 8
    const int grid = B_N * C_N * 2;              // 8192 (row x chunk-pair)

    act1d_fused<<<grid, BLOCK, 0, stream>>>(x, alpha, wup, wdn, out);
}